// Round 5
// baseline (197.998 us; speedup 1.0000x reference)
//
#include <hip/hip_runtime.h>
#include <hip/hip_bf16.h>
#include <stdint.h>

using bf16 = __hip_bfloat16;

typedef __bf16 bf16x8 __attribute__((ext_vector_type(8)));
typedef float  f32x4  __attribute__((ext_vector_type(4)));

constexpr int Bc = 4, Hh = 8, Dh = 128, S = 2048, Cn = 1024, O3 = 3072;
constexpr float SCALE = 0.08838834764831845f;  // 1/sqrt(128)

// async global->LDS, 16B per lane, wave-uniform LDS base + lane*16 scatter
#define GLDS16(gp, lp)                                               \
  __builtin_amdgcn_global_load_lds(                                  \
      (const __attribute__((address_space(1))) void*)(gp),           \
      (__attribute__((address_space(3))) void*)(lp), 16, 0, 0)

#define WAITVM(N) asm volatile("s_waitcnt vmcnt(" #N ")" ::: "memory")
#define BAR()                                  \
  do {                                         \
    asm volatile("" ::: "memory");             \
    __builtin_amdgcn_s_barrier();              \
    asm volatile("" ::: "memory");             \
  } while (0)

// ---------------------------------------------------------------------------
// BT-GEMM core (m97 structure): acc[m][n] += sum_k A[m][k] * B[n][k]
// 128x128 output tile, 256 threads = 4 waves. Used by the small GEMMs
// (mt, w2) which run at >=1 block/CU with short K.
// ---------------------------------------------------------------------------
__device__ __forceinline__ void gemm_bt_core(
    const bf16* __restrict__ Abase, int lda,
    const bf16* __restrict__ Bbase, int ldb,
    int kIters, f32x4 (&acc)[4][4])
{
  alignas(16) __shared__ bf16 As[128 * 32];
  alignas(16) __shared__ bf16 Bs[128 * 32];
  const int t    = threadIdx.x;
  const int lane = t & 63;
  const int quad = lane >> 4, r16 = lane & 15;
  const int wave = t >> 6;
  const int wm = (wave & 1) * 64, wn = (wave >> 1) * 64;
  const int lrow = lane >> 2;        // 0..15 within a 16-row chunk
  const int lk   = (lane & 3) * 8;   // k-offset (elems)

  const long aOff0 = (long)(wave * 32 + lrow) * lda + lk;
  const long aOff1 = aOff0 + 16l * lda;
  const long bOff0 = (long)(wave * 32 + lrow) * ldb + lk;
  const long bOff1 = bOff0 + 16l * ldb;
  bf16* aL0 = &As[(wave * 32) * 32];
  bf16* aL1 = &As[(wave * 32 + 16) * 32];
  bf16* bL0 = &Bs[(wave * 32) * 32];
  bf16* bL1 = &Bs[(wave * 32 + 16) * 32];

#pragma unroll
  for (int i = 0; i < 4; i++)
#pragma unroll
    for (int j = 0; j < 4; j++) acc[i][j] = {0.f, 0.f, 0.f, 0.f};

  for (int ks = 0; ks < kIters; ++ks) {
    const int k0 = ks * 32;
    __syncthreads();
    GLDS16(Abase + k0 + aOff0, aL0);
    GLDS16(Abase + k0 + aOff1, aL1);
    GLDS16(Bbase + k0 + bOff0, bL0);
    GLDS16(Bbase + k0 + bOff1, bL1);
    __syncthreads();
    bf16x8 af[4], bfr[4];
#pragma unroll
    for (int i = 0; i < 4; i++)
      af[i] = *(const bf16x8*)&As[(wm + i * 16 + r16) * 32 + quad * 8];
#pragma unroll
    for (int j = 0; j < 4; j++)
      bfr[j] = *(const bf16x8*)&Bs[(wn + j * 16 + r16) * 32 + quad * 8];
#pragma unroll
    for (int i = 0; i < 4; i++)
#pragma unroll
      for (int j = 0; j < 4; j++)
        acc[i][j] = __builtin_amdgcn_mfma_f32_16x16x32_bf16(af[i], bfr[j], acc[i][j], 0, 0, 0);
  }
}

__device__ __forceinline__ void store_bf16_tile(
    f32x4 (&acc)[4][4], bf16* __restrict__ Cp, int ldc)
{
  const int t = threadIdx.x;
  const int lane = t & 63;
  const int quad = lane >> 4, r16 = lane & 15;
  const int wave = t >> 6;
  const int wm = (wave & 1) * 64, wn = (wave >> 1) * 64;
#pragma unroll
  for (int i = 0; i < 4; i++)
#pragma unroll
    for (int j = 0; j < 4; j++)
#pragma unroll
      for (int r = 0; r < 4; r++) {
        const int row = wm + i * 16 + quad * 4 + r;
        const int col = wn + j * 16 + r16;
        Cp[(long)row * ldc + col] = __float2bfloat16(acc[i][j][r]);
      }
}

__device__ __forceinline__ void store_f32_tile(
    f32x4 (&acc)[4][4], float* __restrict__ Cp, int ldc)
{
  const int t = threadIdx.x;
  const int lane = t & 63;
  const int quad = lane >> 4, r16 = lane & 15;
  const int wave = t >> 6;
  const int wm = (wave & 1) * 64, wn = (wave >> 1) * 64;
#pragma unroll
  for (int i = 0; i < 4; i++)
#pragma unroll
    for (int j = 0; j < 4; j++)
#pragma unroll
      for (int r = 0; r < 4; r++) {
        const int row = wm + i * 16 + quad * 4 + r;
        const int col = wn + j * 16 + r16;
        Cp[(long)row * ldc + col] = acc[i][j][r];
      }
}

// ---------------------------------------------------------------------------
// kv body: 256x256 pipelined GEMM, KV = Wkv . x (BT form, all batches).
//   M=2048, N=8192, K=1024. orig in [0,256). 4 LDS buffers (128 KiB).
// Per K-tile, 2 barriers with ds_read/MFMA overlap (proven r3):
//   [BAR A] stage(t+3) | ds_read(p2 A-frags) | MFMA p1 (regs preloaded)
//   vmcnt(8) [BAR B]   MFMA p2 | ds_read(tile t+1 p1 frags)
// XCD grouping (proven r4): XCD = orig&7 owns 4 nt x all 8 mt.
// ---------------------------------------------------------------------------
__device__ __forceinline__ void kv_body(
    const bf16* __restrict__ WkvB, const bf16* __restrict__ xT,
    bf16* __restrict__ KV, bf16* sm, int orig)
{
  constexpr int NT = Cn / 32;  // 32 K-tiles
  const int mt = orig >> 5;                               // 0..7  (o' tile)
  const int nt = ((orig & 7) << 2) | ((orig >> 3) & 3);   // 0..31 (s tile)
  const int m0 = mt * 256;

  const int tid  = threadIdx.x;
  const int lane = tid & 63;
  const int w    = tid >> 6;
  const int quad = lane >> 4, r16 = lane & 15;
  const int wm = (w >> 2) * 128;
  const int wn = (w & 3) * 64;

  const int srow = w * 16 + (lane >> 2);
  const int cx   = (lane & 3) ^ ((lane >> 3) & 3);   // inverse-swizzled k-chunk
  const bf16* Ag = WkvB + (long)(m0 + srow) * Cn + cx * 8;
  const bf16* Bg = xT + (long)((long)nt * 256 + srow) * Cn + cx * 8;
  const int ldsW = w * 512;

#define KV8_STAGE_A(tt)                                                   \
  do {                                                                    \
    const int k0_ = (tt) * 32, bb_ = ((tt) & 3) * 16384;                  \
    GLDS16(Ag + k0_,             &sm[bb_ + ldsW]);                        \
    GLDS16(Ag + 128l * Cn + k0_, &sm[bb_ + 4096 + ldsW]);                 \
  } while (0)
#define KV8_STAGE_B(tt)                                                   \
  do {                                                                    \
    const int k0_ = (tt) * 32, bb_ = ((tt) & 3) * 16384;                  \
    GLDS16(Bg + k0_,             &sm[bb_ + 8192 + ldsW]);                 \
    GLDS16(Bg + 128l * Cn + k0_, &sm[bb_ + 8192 + 4096 + ldsW]);          \
  } while (0)

  const int sc8 = (quad ^ ((r16 >> 1) & 3)) * 8;  // swizzled chunk, 2-way=free

  f32x4 acc[8][4];
#pragma unroll
  for (int m = 0; m < 8; m++)
#pragma unroll
    for (int n = 0; n < 4; n++) acc[m][n] = {0.f, 0.f, 0.f, 0.f};

  // prologue: stage tiles 0,1,2 (12 loads/wave); retire tile 0's 4
  KV8_STAGE_A(0); KV8_STAGE_B(0);
  KV8_STAGE_A(1); KV8_STAGE_B(1);
  KV8_STAGE_A(2); KV8_STAGE_B(2);
  WAITVM(8);
  BAR();

  bf16x8 af0[4], bfr0[4], af1[4];
  {  // preload tile 0 phase-1 fragments
    const bf16* Ab = &sm[0];
    const bf16* Bb = Ab + 8192;
#pragma unroll
    for (int n = 0; n < 4; n++)
      bfr0[n] = *(const bf16x8*)&Bb[(wn + n * 16 + r16) * 32 + sc8];
#pragma unroll
    for (int m = 0; m < 4; m++)
      af0[m] = *(const bf16x8*)&Ab[(wm + m * 16 + r16) * 32 + sc8];
  }

#pragma unroll 4
  for (int tt = 0; tt < NT; ++tt) {
    const bf16* Ab = &sm[(tt & 3) * 16384];

    BAR();  // BAR A: buf (t-1)&3 fully read -> safe to stage t+3 into it
    if (tt + 3 < NT) { KV8_STAGE_A(tt + 3); KV8_STAGE_B(tt + 3); }
#pragma unroll
    for (int m = 0; m < 4; m++)
      af1[m] = *(const bf16x8*)&Ab[(wm + (m + 4) * 16 + r16) * 32 + sc8];
    __builtin_amdgcn_s_setprio(1);
#pragma unroll
    for (int m = 0; m < 4; m++)
#pragma unroll
      for (int n = 0; n < 4; n++)
        acc[m][n] = __builtin_amdgcn_mfma_f32_16x16x32_bf16(af0[m], bfr0[n], acc[m][n], 0, 0, 0);
    __builtin_amdgcn_s_setprio(0);

    if (tt <= NT - 4)      { WAITVM(8); }
    else if (tt == NT - 3) { WAITVM(4); }
    else if (tt == NT - 2) { WAITVM(0); }
    BAR();  // BAR B: every wave's vmcnt retired tile t+1 -> buf t+1 readable

    __builtin_amdgcn_s_setprio(1);
#pragma unroll
    for (int m = 0; m < 4; m++)
#pragma unroll
      for (int n = 0; n < 4; n++)
        acc[m + 4][n] = __builtin_amdgcn_mfma_f32_16x16x32_bf16(af1[m], bfr0[n], acc[m + 4][n], 0, 0, 0);
    __builtin_amdgcn_s_setprio(0);

    if (tt + 1 < NT) {  // look-ahead: tile t+1 phase-1 fragments
      const bf16* Ab2 = &sm[((tt + 1) & 3) * 16384];
      const bf16* Bb2 = Ab2 + 8192;
#pragma unroll
      for (int n = 0; n < 4; n++)
        bfr0[n] = *(const bf16x8*)&Bb2[(wn + n * 16 + r16) * 32 + sc8];
#pragma unroll
      for (int m = 0; m < 4; m++)
        af0[m] = *(const bf16x8*)&Ab2[(wm + m * 16 + r16) * 32 + sc8];
    }
  }

  // epilogue: per-wave 128x64 sub-tile -> KV[b][o'][s]
  bf16* Cp = KV + (long)(nt >> 3) * 2048 * S + (long)m0 * S + (nt & 7) * 256;
#pragma unroll
  for (int m = 0; m < 8; m++)
#pragma unroll
    for (int n = 0; n < 4; n++)
#pragma unroll
      for (int r = 0; r < 4; r++) {
        const int row = wm + m * 16 + quad * 4 + r;
        const int col = wn + n * 16 + r16;
        Cp[(long)row * S + col] = __float2bfloat16(acc[m][n][r]);
      }
#undef KV8_STAGE_A
#undef KV8_STAGE_B
}

// ---------------------------------------------------------------------------
// qt body: 128x256 pipelined GEMM, QT[b][s][u] = sum_c xT[b][s][c]*Wq[u][c].
//   orig in [0,256): b=orig>>6, mt=(orig>>2)&15, nt=orig&3.
//   LDS: 4 buffers x (A 4096 + B 8192) elems = 96 KiB (fits kv's 128 KiB).
// ---------------------------------------------------------------------------
__device__ __forceinline__ void qt_body(
    const bf16* __restrict__ xT, const bf16* __restrict__ WqB,
    bf16* __restrict__ QT, bf16* sm, int orig)
{
  constexpr int NT = Cn / 32;  // 32
  const int b  = orig >> 6;          // 0..3
  const int mt = (orig >> 2) & 15;   // 0..15 (s tile of 128)
  const int nt = orig & 3;           // 0..3  (u tile of 256)
  const int m0 = mt * 128, n0 = nt * 256;

  const int tid  = threadIdx.x;
  const int lane = tid & 63;
  const int w    = tid >> 6;
  const int quad = lane >> 4, r16 = lane & 15;
  const int wm = (w >> 2) * 64;
  const int wn = (w & 3) * 64;

  const int srow = w * 16 + (lane >> 2);
  const int cx   = (lane & 3) ^ ((lane >> 3) & 3);
  const bf16* Ag = xT + (long)b * S * Cn + (long)(m0 + srow) * Cn + cx * 8;
  const bf16* Bg = WqB + (long)(n0 + srow) * Cn + cx * 8;
  const int ldsW = w * 512;

#define QT_STAGE(tt)                                                      \
  do {                                                                    \
    const int k0_ = (tt) * 32, bb_ = ((tt) & 3) * 12288;                  \
    GLDS16(Ag + k0_,             &sm[bb_ + ldsW]);                        \
    GLDS16(Bg + k0_,             &sm[bb_ + 4096 + ldsW]);                 \
    GLDS16(Bg + 128l * Cn + k0_, &sm[bb_ + 8192 + ldsW]);                 \
  } while (0)

  const int sc8 = (quad ^ ((r16 >> 1) & 3)) * 8;

  f32x4 acc[4][4];
#pragma unroll
  for (int m = 0; m < 4; m++)
#pragma unroll
    for (int n = 0; n < 4; n++) acc[m][n] = {0.f, 0.f, 0.f, 0.f};

  QT_STAGE(0); QT_STAGE(1); QT_STAGE(2);
  WAITVM(6);
  BAR();

  bf16x8 af0[2], bfr0[4], af1[2];
  {
    const bf16* Ab = &sm[0];
    const bf16* Bb = Ab + 4096;
#pragma unroll
    for (int n = 0; n < 4; n++)
      bfr0[n] = *(const bf16x8*)&Bb[(wn + n * 16 + r16) * 32 + sc8];
#pragma unroll
    for (int m = 0; m < 2; m++)
      af0[m] = *(const bf16x8*)&Ab[(wm + m * 16 + r16) * 32 + sc8];
  }

#pragma unroll 4
  for (int tt = 0; tt < NT; ++tt) {
    const bf16* Ab = &sm[(tt & 3) * 12288];

    BAR();  // BAR A
    if (tt + 3 < NT) QT_STAGE(tt + 3);
#pragma unroll
    for (int m = 0; m < 2; m++)
      af1[m] = *(const bf16x8*)&Ab[(wm + (m + 2) * 16 + r16) * 32 + sc8];
    __builtin_amdgcn_s_setprio(1);
#pragma unroll
    for (int m = 0; m < 2; m++)
#pragma unroll
      for (int n = 0; n < 4; n++)
        acc[m][n] = __builtin_amdgcn_mfma_f32_16x16x32_bf16(af0[m], bfr0[n], acc[m][n], 0, 0, 0);
    __builtin_amdgcn_s_setprio(0);

    if (tt <= NT - 4)      { WAITVM(6); }
    else if (tt == NT - 3) { WAITVM(3); }
    else if (tt == NT - 2) { WAITVM(0); }
    BAR();  // BAR B

    __builtin_amdgcn_s_setprio(1);
#pragma unroll
    for (int m = 0; m < 2; m++)
#pragma unroll
      for (int n = 0; n < 4; n++)
        acc[m + 2][n] = __builtin_amdgcn_mfma_f32_16x16x32_bf16(af1[m], bfr0[n], acc[m + 2][n], 0, 0, 0);
    __builtin_amdgcn_s_setprio(0);

    if (tt + 1 < NT) {
      const bf16* Ab2 = &sm[((tt + 1) & 3) * 12288];
      const bf16* Bb2 = Ab2 + 4096;
#pragma unroll
      for (int n = 0; n < 4; n++)
        bfr0[n] = *(const bf16x8*)&Bb2[(wn + n * 16 + r16) * 32 + sc8];
#pragma unroll
      for (int m = 0; m < 2; m++)
        af0[m] = *(const bf16x8*)&Ab2[(wm + m * 16 + r16) * 32 + sc8];
    }
  }

  // epilogue: per-wave 64x64 sub-tile -> QT[b][s][u], bf16
  bf16* Cp = QT + (long)b * S * Cn + (long)m0 * Cn + n0;
#pragma unroll
  for (int m = 0; m < 4; m++)
#pragma unroll
    for (int n = 0; n < 4; n++)
#pragma unroll
      for (int r = 0; r < 4; r++) {
        const int row = wm + m * 16 + quad * 4 + r;
        const int col = wn + n * 16 + r16;
        Cp[(long)row * Cn + col] = __float2bfloat16(acc[m][n][r]);
      }
#undef QT_STAGE
}

// ---------------------------------------------------------------------------
// Fused dispatch: blocks 0-255 = kv, 256-511 = qt. Independent outputs.
// CUs finishing a kv block immediately pick up a qt block (tail-fill).
// ---------------------------------------------------------------------------
__global__ __launch_bounds__(512, 2) void k_kvqt8(
    const bf16* __restrict__ WkvB, const bf16* __restrict__ xT,
    bf16* __restrict__ KV, const bf16* __restrict__ WqB, bf16* __restrict__ QT)
{
  alignas(16) __shared__ bf16 smem[4 * 16384];  // 128 KiB (qt uses 96 KiB)
  const int bid = blockIdx.x;
  if (bid < 256) kv_body(WkvB, xT, KV, smem, bid);
  else           qt_body(xT, WqB, QT, smem, bid - 256);
}

// ---------------------------------------------------------------------------
// Fused prep: z<4 -> xT[b] = bf16(x[b]^T); z==4 -> weights f32->bf16.
// ---------------------------------------------------------------------------
__global__ __launch_bounds__(256) void k_prep(
    const float* __restrict__ x, bf16* __restrict__ xT,
    const float* __restrict__ Wqkv, const float* __restrict__ Wout,
    bf16* __restrict__ WqkvB, bf16* __restrict__ WoutB)
{
  __shared__ bf16 tile[32][33];
  if (blockIdx.z < 4) {
    const float* ip = x + (long)blockIdx.z * 1024 * 2048;
    bf16* op = xT + (long)blockIdx.z * 2048 * 1024;
    const int c0 = blockIdx.x * 32, r0 = blockIdx.y * 32;
    const int tx = threadIdx.x & 31, ty = threadIdx.x >> 5;  // 32 x 8
#pragma unroll
    for (int i = 0; i < 32; i += 8)
      tile[ty + i][tx] = __float2bfloat16(ip[(long)(r0 + ty + i) * 2048 + c0 + tx]);
    __syncthreads();
#pragma unroll
    for (int i = 0; i < 32; i += 8)
      op[(long)(c0 + ty + i) * 1024 + r0 + tx] = tile[tx][ty + i];
  } else {
    // 2048 blocks x 256 thr x 2 vec4 = 1,048,576 float4s
    const long blk = (long)blockIdx.x + (long)blockIdx.y * 64;
#pragma unroll
    for (int i = 0; i < 2; i++) {
      const long v = blk * 512 + i * 256 + threadIdx.x;
      const bool isQ = v < 786432;
      const float4 f = isQ ? ((const float4*)Wqkv)[v] : ((const float4*)Wout)[v - 786432];
      bf16 tmp[4];
      tmp[0] = __float2bfloat16(f.x);
      tmp[1] = __float2bfloat16(f.y);
      tmp[2] = __float2bfloat16(f.z);
      tmp[3] = __float2bfloat16(f.w);
      ushort4 u = *(ushort4*)tmp;
      if (isQ) ((ushort4*)WqkvB)[v] = u;
      else     ((ushort4*)WoutB)[v - 786432] = u;
    }
  }
}

// ---------------------------------------------------------------------------
// 128x256 pipelined GEMM (overlap schedule): out = W2[b] . Q[b] -> f32.
// ---------------------------------------------------------------------------
__global__ __launch_bounds__(512, 2) void k_gemm_out8(
    const bf16* __restrict__ W2, const bf16* __restrict__ QT, float* __restrict__ out)
{
  constexpr int NT = Cn / 32;  // 32
  alignas(16) __shared__ bf16 smem[4 * 12288];  // 96 KiB

  const int orig = blockIdx.x;
  const int swz  = (orig & 7) * 32 + (orig >> 3);
  const int b  = swz >> 6;
  const int mt = (swz >> 3) & 7;
  const int nt = swz & 7;
  const int m0 = mt * 128, n0 = nt * 256;

  const int tid  = threadIdx.x;
  const int lane = tid & 63;
  const int w    = tid >> 6;
  const int quad = lane >> 4, r16 = lane & 15;
  const int wm = (w >> 2) * 64;   // 2 m-groups of 64
  const int wn = (w & 3) * 64;    // 4 n-groups of 64 (covers 256)

  const int srow = w * 16 + (lane >> 2);           // 0..127
  const int cx   = (lane & 3) ^ ((lane >> 3) & 3);
  const bf16* Ag = W2 + (long)b * Cn * Cn + (long)(m0 + srow) * Cn + cx * 8;
  const bf16* Bg = QT + (long)b * S * Cn + (long)(n0 + srow) * Cn + cx * 8;
  const int ldsW = w * 512;

#define OUT_STAGE(tt)                                                     \
  do {                                                                    \
    const int k0_ = (tt) * 32, bb_ = ((tt) & 3) * 12288;                  \
    GLDS16(Ag + k0_,             &smem[bb_ + ldsW]);                      \
    GLDS16(Bg + k0_,             &smem[bb_ + 4096 + ldsW]);               \
    GLDS16(Bg + 128l * Cn + k0_, &smem[bb_ + 8192 + ldsW]);               \
  } while (0)

  const int sc8 = (quad ^ ((r16 >> 1) & 3)) * 8;

  f32x4 acc[4][4];
#pragma unroll
  for (int m = 0; m < 4; m++)
#pragma unroll
    for (int n = 0; n < 4; n++) acc[m][n] = {0.f, 0.f, 0.f, 0.f};

  OUT_STAGE(0); OUT_STAGE(1); OUT_STAGE(2);
  WAITVM(6);
  BAR();

  bf16x8 af0[2], bfr0[4], af1[2];
  {
    const bf16* Ab = &smem[0];
    const bf16* Bb = Ab + 4096;
#pragma unroll
    for (int n = 0; n < 4; n++)
      bfr0[n] = *(const bf16x8*)&Bb[(wn + n * 16 + r16) * 32 + sc8];
#pragma unroll
    for (int m = 0; m < 2; m++)
      af0[m] = *(const bf16x8*)&Ab[(wm + m * 16 + r16) * 32 + sc8];
  }

#pragma unroll 4
  for (int tt = 0; tt < NT; ++tt) {
    const bf16* Ab = &smem[(tt & 3) * 12288];

    BAR();  // BAR A
    if (tt + 3 < NT) OUT_STAGE(tt + 3);
#pragma unroll
    for (int m = 0; m < 2; m++)
      af1[m] = *(const bf16x8*)&Ab[(wm + (m + 2) * 16 + r16) * 32 + sc8];
    __builtin_amdgcn_s_setprio(1);
#pragma unroll
    for (int m = 0; m < 2; m++)
#pragma unroll
      for (int n = 0; n < 4; n++)
        acc[m][n] = __builtin_amdgcn_mfma_f32_16x16x32_bf16(af0[m], bfr0[n], acc[m][n], 0, 0, 0);
    __builtin_amdgcn_s_setprio(0);

    if (tt <= NT - 4)      { WAITVM(6); }
    else if (tt == NT - 3) { WAITVM(3); }
    else if (tt == NT - 2) { WAITVM(0); }
    BAR();  // BAR B

    __builtin_amdgcn_s_setprio(1);
#pragma unroll
    for (int m = 0; m < 2; m++)
#pragma unroll
      for (int n = 0; n < 4; n++)
        acc[m + 2][n] = __builtin_amdgcn_mfma_f32_16x16x32_bf16(af1[m], bfr0[n], acc[m + 2][n], 0, 0, 0);
    __builtin_amdgcn_s_setprio(0);

    if (tt + 1 < NT) {
      const bf16* Ab2 = &smem[((tt + 1) & 3) * 12288];
      const bf16* Bb2 = Ab2 + 4096;
#pragma unroll
      for (int n = 0; n < 4; n++)
        bfr0[n] = *(const bf16x8*)&Bb2[(wn + n * 16 + r16) * 32 + sc8];
#pragma unroll
      for (int m = 0; m < 2; m++)
        af0[m] = *(const bf16x8*)&Ab2[(wm + m * 16 + r16) * 32 + sc8];
    }
  }

  float* Cp = out + (long)b * Cn * S + (long)m0 * S + n0;
#pragma unroll
  for (int m = 0; m < 4; m++)
#pragma unroll
    for (int n = 0; n < 4; n++)
#pragma unroll
      for (int r = 0; r < 4; r++) {
        const int row = wm + m * 16 + quad * 4 + r;
        const int col = wn + n * 16 + r16;
        Cp[(long)row * S + col] = acc[m][n][r];
      }
#undef OUT_STAGE
}

// ---- MTpart[chunk][z][e][d] = K_h . V_h^T over a 256-wide s-chunk ----
__global__ __launch_bounds__(256) void k_gemm_mt(
    const bf16* __restrict__ KV, float* __restrict__ MTpart)
{
  const int chunk = blockIdx.x;               // 8 chunks of 256 along s
  const int z = blockIdx.y;                   // b*8 + h
  const int b = z >> 3, h = z & 7;
  const bf16* base = KV + (long)b * 2048 * S;
  const bf16* A  = base + (long)(h * Dh) * S + chunk * 256;
  const bf16* Bp = base + (long)(1024 + h * Dh) * S + chunk * 256;
  f32x4 acc[4][4];
  gemm_bt_core(A, S, Bp, S, 8, acc);
  store_f32_tile(acc, MTpart + ((long)chunk * 32 + z) * (Dh * Dh), Dh);
}

// ---- MbT[z][e][d] = bf16(SCALE * sum_chunk MTpart) ----
__global__ __launch_bounds__(256) void k_reduce_mt(
    const float* __restrict__ MTpart, bf16* __restrict__ MbT)
{
  const long i = (long)blockIdx.x * 256 + threadIdx.x;  // 524,288 total
  float s = 0.f;
#pragma unroll
  for (int c = 0; c < 8; c++) s += MTpart[(long)c * 32 * Dh * Dh + i];
  MbT[i] = __float2bfloat16(s * SCALE);
}

// ---- W2[b][o][h*128+e] = sum_d Wout[o][h*128+d] * MbT[b,h][e][d] ----
__global__ __launch_bounds__(256) void k_gemm_w2(
    const bf16* __restrict__ WoutB, const bf16* __restrict__ MbT, bf16* __restrict__ W2)
{
  const int m0 = blockIdx.x * 128;
  const int h = blockIdx.y, b = blockIdx.z;
  const int z = b * 8 + h;
  f32x4 acc[4][4];
  gemm_bt_core(WoutB + (long)m0 * Cn + h * Dh, Cn,
               MbT + (long)z * Dh * Dh, Dh, 4, acc);
  store_bf16_tile(acc, W2 + (long)b * Cn * Cn + (long)m0 * Cn + h * Dh, Cn);
}

extern "C" void kernel_launch(void* const* d_in, const int* in_sizes, int n_in,
                              void* d_out, int out_size, void* d_ws, size_t ws_size,
                              hipStream_t stream)
{
  const float* x    = (const float*)d_in[0];  // (4,1024,2048) f32
  const float* Wqkv = (const float*)d_in[1];  // (3072,1024)   f32
  const float* Wout = (const float*)d_in[2];  // (1024,1024)   f32
  float* out = (float*)d_out;                 // (4,1024,2048) f32

  char* ws = (char*)d_ws;
  bf16*  KV     = (bf16*)ws;                     // 33,554,432 B
  bf16*  xT     = (bf16*)(ws + 33554432);        // 16,777,216 B
  bf16*  QT     = (bf16*)(ws + 50331648);        // 16,777,216 B (dedicated now)
  bf16*  WqkvB  = (bf16*)(ws + 67108864);        //  6,291,456 B
  bf16*  WoutB  = (bf16*)(ws + 73400320);        //  2,097,152 B
  bf16*  MbT    = (bf16*)(ws + 75497472);        //  1,048,576 B
  bf16*  W2     = (bf16*)(ws + 76546048);        //  8,388,608 B (end 84,934,656)
  bf16*  WkvB   = WqkvB + (long)Cn * Cn;         // K,V rows of WqkvB
  float* MTpart = out;                           // d_out as 16.7 MB f32 scratch
                                                 // (dead until k_gemm_out8,
                                                 //  which overwrites fully)

  // prep: xT transpose+cvt (z<4) + weights cvt (z==4), one dispatch
  k_prep<<<dim3(64, 32, 5), 256, 0, stream>>>(x, xT, Wqkv, Wout, WqkvB, WoutB);
  // KV GEMM (blocks 0-255) + QT GEMM (blocks 256-511) fused: tail-fill
  k_kvqt8<<<dim3(512), 512, 0, stream>>>(WkvB, xT, KV, WqkvB, QT);
  // MT partials: K_h . V_h^T over 8 s-chunks -> d_out scratch
  k_gemm_mt<<<dim3(8, 32), 256, 0, stream>>>(KV, MTpart);
  // MbT = bf16(SCALE * sum of partials)
  k_reduce_mt<<<dim3(2048), 256, 0, stream>>>(MTpart, MbT);
  // W2[b] = Wout . blockdiag(scale*M): folded output weights
  k_gemm_w2<<<dim3(8, 8, 4), 256, 0, stream>>>(WoutB, MbT, W2);
  // out[b] = W2[b] . Q[b]  (f32 output, overwrites scratch)
  k_gemm_out8<<<dim3(256), 512, 0, stream>>>(W2, QT, out);
}

// Round 6
// 196.587 us; speedup vs baseline: 1.0072x; 1.0072x over previous
//
#include <hip/hip_runtime.h>
#include <hip/hip_bf16.h>
#include <stdint.h>

using bf16 = __hip_bfloat16;

typedef __bf16 bf16x8 __attribute__((ext_vector_type(8)));
typedef float  f32x4  __attribute__((ext_vector_type(4)));

constexpr int Bc = 4, Hh = 8, Dh = 128, S = 2048, Cn = 1024, O3 = 3072;
constexpr float SCALE = 0.08838834764831845f;  // 1/sqrt(128)

// async global->LDS, 16B per lane, wave-uniform LDS base + lane*16 scatter
#define GLDS16(gp, lp)                                               \
  __builtin_amdgcn_global_load_lds(                                  \
      (const __attribute__((address_space(1))) void*)(gp),           \
      (__attribute__((address_space(3))) void*)(lp), 16, 0, 0)

#define WAITVM(N) asm volatile("s_waitcnt vmcnt(" #N ")" ::: "memory")
#define BAR()                                  \
  do {                                         \
    asm volatile("" ::: "memory");             \
    __builtin_amdgcn_s_barrier();              \
    asm volatile("" ::: "memory");             \
  } while (0)

// ---------------------------------------------------------------------------
// BT-GEMM core (m97 structure): 128x128 tile, 256 threads = 4 waves.
// Used by the small GEMMs (mt, w2).
// ---------------------------------------------------------------------------
__device__ __forceinline__ void gemm_bt_core(
    const bf16* __restrict__ Abase, int lda,
    const bf16* __restrict__ Bbase, int ldb,
    int kIters, f32x4 (&acc)[4][4])
{
  alignas(16) __shared__ bf16 As[128 * 32];
  alignas(16) __shared__ bf16 Bs[128 * 32];
  const int t    = threadIdx.x;
  const int lane = t & 63;
  const int quad = lane >> 4, r16 = lane & 15;
  const int wave = t >> 6;
  const int wm = (wave & 1) * 64, wn = (wave >> 1) * 64;
  const int lrow = lane >> 2;
  const int lk   = (lane & 3) * 8;

  const long aOff0 = (long)(wave * 32 + lrow) * lda + lk;
  const long aOff1 = aOff0 + 16l * lda;
  const long bOff0 = (long)(wave * 32 + lrow) * ldb + lk;
  const long bOff1 = bOff0 + 16l * ldb;
  bf16* aL0 = &As[(wave * 32) * 32];
  bf16* aL1 = &As[(wave * 32 + 16) * 32];
  bf16* bL0 = &Bs[(wave * 32) * 32];
  bf16* bL1 = &Bs[(wave * 32 + 16) * 32];

#pragma unroll
  for (int i = 0; i < 4; i++)
#pragma unroll
    for (int j = 0; j < 4; j++) acc[i][j] = {0.f, 0.f, 0.f, 0.f};

  for (int ks = 0; ks < kIters; ++ks) {
    const int k0 = ks * 32;
    __syncthreads();
    GLDS16(Abase + k0 + aOff0, aL0);
    GLDS16(Abase + k0 + aOff1, aL1);
    GLDS16(Bbase + k0 + bOff0, bL0);
    GLDS16(Bbase + k0 + bOff1, bL1);
    __syncthreads();
    bf16x8 af[4], bfr[4];
#pragma unroll
    for (int i = 0; i < 4; i++)
      af[i] = *(const bf16x8*)&As[(wm + i * 16 + r16) * 32 + quad * 8];
#pragma unroll
    for (int j = 0; j < 4; j++)
      bfr[j] = *(const bf16x8*)&Bs[(wn + j * 16 + r16) * 32 + quad * 8];
#pragma unroll
    for (int i = 0; i < 4; i++)
#pragma unroll
      for (int j = 0; j < 4; j++)
        acc[i][j] = __builtin_amdgcn_mfma_f32_16x16x32_bf16(af[i], bfr[j], acc[i][j], 0, 0, 0);
  }
}

__device__ __forceinline__ void store_bf16_tile(
    f32x4 (&acc)[4][4], bf16* __restrict__ Cp, int ldc)
{
  const int t = threadIdx.x;
  const int lane = t & 63;
  const int quad = lane >> 4, r16 = lane & 15;
  const int wave = t >> 6;
  const int wm = (wave & 1) * 64, wn = (wave >> 1) * 64;
#pragma unroll
  for (int i = 0; i < 4; i++)
#pragma unroll
    for (int j = 0; j < 4; j++)
#pragma unroll
      for (int r = 0; r < 4; r++) {
        const int row = wm + i * 16 + quad * 4 + r;
        const int col = wn + j * 16 + r16;
        Cp[(long)row * ldc + col] = __float2bfloat16(acc[i][j][r]);
      }
}

__device__ __forceinline__ void store_f32_tile(
    f32x4 (&acc)[4][4], float* __restrict__ Cp, int ldc)
{
  const int t = threadIdx.x;
  const int lane = t & 63;
  const int quad = lane >> 4, r16 = lane & 15;
  const int wave = t >> 6;
  const int wm = (wave & 1) * 64, wn = (wave >> 1) * 64;
#pragma unroll
  for (int i = 0; i < 4; i++)
#pragma unroll
    for (int j = 0; j < 4; j++)
#pragma unroll
      for (int r = 0; r < 4; r++) {
        const int row = wm + i * 16 + quad * 4 + r;
        const int col = wn + j * 16 + r16;
        Cp[(long)row * ldc + col] = acc[i][j][r];
      }
}

// ===========================================================================
// Pipelined 8-wave cores, v4: 64x64 acc/wave (64 regs), 3 LDS buffers
// (72 KiB), stage t+2, counted vmcnt(3), 2 blocks/CU via launch_bounds(512,4).
// Window t (2 barriers):
//   [BAR A] stage(t+2)->buf[t+2] | ds_read af1 from buf[t] | MFMA p1
//   vmcnt(3) [BAR B] MFMA p2 | lookahead af0/bfr0 from buf[t+1]
// Safety (same proof as verified 4-buf version, depth-1 shallower):
//  WAR: buf[t+2]=buf[t-1]; all reads of buf[t-1] precede BAR A(t).
//  RAW: each wave's vmcnt(3) retires its stage(t+1) 3 loads (FIFO); BAR B
//  orders before lookahead. Tails: vmcnt(3) ... vmcnt(0) at tt==NT-2.
// ===========================================================================

// ---- kv body: KV = Wkv . x, tile 256(o') x 128(s), 512 blocks ----
__device__ __forceinline__ void kv_body(
    const bf16* __restrict__ WkvB, const bf16* __restrict__ xT,
    bf16* __restrict__ KV, bf16* sm, int orig)
{
  constexpr int NT = Cn / 32;  // 32 K-tiles
  // XCD = orig&7 owns 8 consecutive nt (1024 s-rows = 2MB B, L2-resident)
  const int mt = orig >> 6;                               // 0..7
  const int nt = ((orig & 7) << 3) | ((orig >> 3) & 7);   // 0..63
  const int m0 = mt * 256;

  const int tid  = threadIdx.x;
  const int lane = tid & 63;
  const int w    = tid >> 6;
  const int quad = lane >> 4, r16 = lane & 15;
  const int wm = (w >> 1) * 64;   // 4 M-groups of 64
  const int wn = (w & 1) * 64;    // 2 N-groups of 64

  const int srow = w * 16 + (lane >> 2);             // 0..127
  const int cx   = (lane & 3) ^ ((lane >> 3) & 3);   // inverse-swizzled chunk
  const bf16* Ag = WkvB + (long)(m0 + srow) * Cn + cx * 8;
  const bf16* Bg = xT + (long)((long)nt * 128 + srow) * Cn + cx * 8;
  const int ldsW = w * 512;

  // buf layout: A 8192 elems (256 rows x 32) then B 4096 (128 rows x 32)
#define KV_STAGE(base, tt)                                                \
  do {                                                                    \
    const int k0_ = (tt) * 32;                                            \
    GLDS16(Ag + k0_,             (base) + ldsW);                          \
    GLDS16(Ag + 128l * Cn + k0_, (base) + 4096 + ldsW);                   \
    GLDS16(Bg + k0_,             (base) + 8192 + ldsW);                   \
  } while (0)

  const int sc8 = (quad ^ ((r16 >> 1) & 3)) * 8;

  f32x4 acc[4][4];
#pragma unroll
  for (int m = 0; m < 4; m++)
#pragma unroll
    for (int n = 0; n < 4; n++) acc[m][n] = {0.f, 0.f, 0.f, 0.f};

  bf16* bufc = sm;              // buf[t]
  bf16* bufn = sm + 12288;      // buf[t+1]
  bf16* bufs = sm + 24576;      // buf[t+2] stage target

  KV_STAGE(bufc, 0); KV_STAGE(bufn, 1);
  WAITVM(3);   // retire tile 0's 3 loads
  BAR();

  bf16x8 af0[2], af1[2], bfr0[4];
#pragma unroll
  for (int n = 0; n < 4; n++)
    bfr0[n] = *(const bf16x8*)&bufc[8192 + (wn + n * 16 + r16) * 32 + sc8];
#pragma unroll
  for (int m = 0; m < 2; m++)
    af0[m] = *(const bf16x8*)&bufc[(wm + m * 16 + r16) * 32 + sc8];

#pragma unroll 3
  for (int tt = 0; tt < NT; ++tt) {
    BAR();  // BAR A: buf[t-1] fully read -> safe stage target
    if (tt + 2 < NT) KV_STAGE(bufs, tt + 2);
#pragma unroll
    for (int m = 0; m < 2; m++)
      af1[m] = *(const bf16x8*)&bufc[(wm + (m + 2) * 16 + r16) * 32 + sc8];
    __builtin_amdgcn_s_setprio(1);
#pragma unroll
    for (int m = 0; m < 2; m++)
#pragma unroll
      for (int n = 0; n < 4; n++)
        acc[m][n] = __builtin_amdgcn_mfma_f32_16x16x32_bf16(af0[m], bfr0[n], acc[m][n], 0, 0, 0);
    __builtin_amdgcn_s_setprio(0);

    if (tt < NT - 2)       { WAITVM(3); }
    else if (tt == NT - 2) { WAITVM(0); }
    BAR();  // BAR B: buf[t+1] landed for every wave

    __builtin_amdgcn_s_setprio(1);
#pragma unroll
    for (int m = 0; m < 2; m++)
#pragma unroll
      for (int n = 0; n < 4; n++)
        acc[m + 2][n] = __builtin_amdgcn_mfma_f32_16x16x32_bf16(af1[m], bfr0[n], acc[m + 2][n], 0, 0, 0);
    __builtin_amdgcn_s_setprio(0);

    if (tt + 1 < NT) {  // lookahead: tile t+1 p1 fragments
#pragma unroll
      for (int n = 0; n < 4; n++)
        bfr0[n] = *(const bf16x8*)&bufn[8192 + (wn + n * 16 + r16) * 32 + sc8];
#pragma unroll
      for (int m = 0; m < 2; m++)
        af0[m] = *(const bf16x8*)&bufn[(wm + m * 16 + r16) * 32 + sc8];
    }
    bf16* t_ = bufc; bufc = bufn; bufn = bufs; bufs = t_;  // rotate
  }

  // epilogue: per-wave 64x64 -> KV[b][o'][s]
  const int b = nt >> 4, scol = (nt & 15) * 128;
  bf16* Cp = KV + (long)b * 2048 * S + (long)m0 * S + scol;
#pragma unroll
  for (int m = 0; m < 4; m++)
#pragma unroll
    for (int n = 0; n < 4; n++)
#pragma unroll
      for (int r = 0; r < 4; r++) {
        const int row = wm + m * 16 + quad * 4 + r;
        const int col = wn + n * 16 + r16;
        Cp[(long)row * S + col] = __float2bfloat16(acc[m][n][r]);
      }
#undef KV_STAGE
}

// ---- qt body: QT[b][s][u] = xT . Wq^T, tile 128(s) x 256(u) ----
__device__ __forceinline__ void qt_body(
    const bf16* __restrict__ xT, const bf16* __restrict__ WqB,
    bf16* __restrict__ QT, bf16* sm, int orig)
{
  constexpr int NT = Cn / 32;
  const int b  = orig >> 6;          // 0..3
  const int mt = (orig >> 2) & 15;   // 0..15
  const int nt = orig & 3;           // 0..3
  const int m0 = mt * 128, n0 = nt * 256;

  const int tid  = threadIdx.x;
  const int lane = tid & 63;
  const int w    = tid >> 6;
  const int quad = lane >> 4, r16 = lane & 15;
  const int wm = (w >> 2) * 64;   // 2 M-groups
  const int wn = (w & 3) * 64;    // 4 N-groups

  const int srow = w * 16 + (lane >> 2);
  const int cx   = (lane & 3) ^ ((lane >> 3) & 3);
  const bf16* Ag = xT + (long)b * S * Cn + (long)(m0 + srow) * Cn + cx * 8;
  const bf16* Bg = WqB + (long)(n0 + srow) * Cn + cx * 8;
  const int ldsW = w * 512;

  // buf layout: A 4096 elems (128 rows) then B 8192 (256 rows)
#define QT_STAGE(base, tt)                                                \
  do {                                                                    \
    const int k0_ = (tt) * 32;                                            \
    GLDS16(Ag + k0_,             (base) + ldsW);                          \
    GLDS16(Bg + k0_,             (base) + 4096 + ldsW);                   \
    GLDS16(Bg + 128l * Cn + k0_, (base) + 8192 + ldsW);                   \
  } while (0)

  const int sc8 = (quad ^ ((r16 >> 1) & 3)) * 8;

  f32x4 acc[4][4];
#pragma unroll
  for (int m = 0; m < 4; m++)
#pragma unroll
    for (int n = 0; n < 4; n++) acc[m][n] = {0.f, 0.f, 0.f, 0.f};

  bf16* bufc = sm;
  bf16* bufn = sm + 12288;
  bf16* bufs = sm + 24576;

  QT_STAGE(bufc, 0); QT_STAGE(bufn, 1);
  WAITVM(3);
  BAR();

  bf16x8 af0[2], af1[2], bfr0[4];
#pragma unroll
  for (int n = 0; n < 4; n++)
    bfr0[n] = *(const bf16x8*)&bufc[4096 + (wn + n * 16 + r16) * 32 + sc8];
#pragma unroll
  for (int m = 0; m < 2; m++)
    af0[m] = *(const bf16x8*)&bufc[(wm + m * 16 + r16) * 32 + sc8];

#pragma unroll 3
  for (int tt = 0; tt < NT; ++tt) {
    BAR();
    if (tt + 2 < NT) QT_STAGE(bufs, tt + 2);
#pragma unroll
    for (int m = 0; m < 2; m++)
      af1[m] = *(const bf16x8*)&bufc[(wm + (m + 2) * 16 + r16) * 32 + sc8];
    __builtin_amdgcn_s_setprio(1);
#pragma unroll
    for (int m = 0; m < 2; m++)
#pragma unroll
      for (int n = 0; n < 4; n++)
        acc[m][n] = __builtin_amdgcn_mfma_f32_16x16x32_bf16(af0[m], bfr0[n], acc[m][n], 0, 0, 0);
    __builtin_amdgcn_s_setprio(0);

    if (tt < NT - 2)       { WAITVM(3); }
    else if (tt == NT - 2) { WAITVM(0); }
    BAR();

    __builtin_amdgcn_s_setprio(1);
#pragma unroll
    for (int m = 0; m < 2; m++)
#pragma unroll
      for (int n = 0; n < 4; n++)
        acc[m + 2][n] = __builtin_amdgcn_mfma_f32_16x16x32_bf16(af1[m], bfr0[n], acc[m + 2][n], 0, 0, 0);
    __builtin_amdgcn_s_setprio(0);

    if (tt + 1 < NT) {
#pragma unroll
      for (int n = 0; n < 4; n++)
        bfr0[n] = *(const bf16x8*)&bufn[4096 + (wn + n * 16 + r16) * 32 + sc8];
#pragma unroll
      for (int m = 0; m < 2; m++)
        af0[m] = *(const bf16x8*)&bufn[(wm + m * 16 + r16) * 32 + sc8];
    }
    bf16* t_ = bufc; bufc = bufn; bufn = bufs; bufs = t_;
  }

  bf16* Cp = QT + (long)b * S * Cn + (long)m0 * Cn + n0;
#pragma unroll
  for (int m = 0; m < 4; m++)
#pragma unroll
    for (int n = 0; n < 4; n++)
#pragma unroll
      for (int r = 0; r < 4; r++) {
        const int row = wm + m * 16 + quad * 4 + r;
        const int col = wn + n * 16 + r16;
        Cp[(long)row * Cn + col] = __float2bfloat16(acc[m][n][r]);
      }
#undef QT_STAGE
}

// ---- fused: blocks 0-511 kv, 512-767 qt. 72 KiB LDS -> 2 blocks/CU ----
__global__ __launch_bounds__(512, 4) void k_kvqt8(
    const bf16* __restrict__ WkvB, const bf16* __restrict__ xT,
    bf16* __restrict__ KV, const bf16* __restrict__ WqB, bf16* __restrict__ QT)
{
  alignas(16) __shared__ bf16 smem[3 * 12288];  // 72 KiB
  const int bid = blockIdx.x;
  if (bid < 512) kv_body(WkvB, xT, KV, smem, bid);
  else           qt_body(xT, WqB, QT, smem, bid - 512);
}

// ---- out = W2[b] . Q[b] -> f32, tile 128(o) x 256(s) ----
__global__ __launch_bounds__(512, 4) void k_gemm_out8(
    const bf16* __restrict__ W2, const bf16* __restrict__ QT, float* __restrict__ out)
{
  constexpr int NT = Cn / 32;
  alignas(16) __shared__ bf16 smem[3 * 12288];  // 72 KiB

  const int orig = blockIdx.x;
  const int swz  = (orig & 7) * 32 + (orig >> 3);
  const int b  = swz >> 6;
  const int mt = (swz >> 3) & 7;
  const int nt = swz & 7;
  const int m0 = mt * 128, n0 = nt * 256;

  const int tid  = threadIdx.x;
  const int lane = tid & 63;
  const int w    = tid >> 6;
  const int quad = lane >> 4, r16 = lane & 15;
  const int wm = (w >> 2) * 64;
  const int wn = (w & 3) * 64;

  const int srow = w * 16 + (lane >> 2);
  const int cx   = (lane & 3) ^ ((lane >> 3) & 3);
  const bf16* Ag = W2 + (long)b * Cn * Cn + (long)(m0 + srow) * Cn + cx * 8;
  const bf16* Bg = QT + (long)b * S * Cn + (long)(n0 + srow) * Cn + cx * 8;
  const int ldsW = w * 512;

#define OUT_STAGE(base, tt)                                               \
  do {                                                                    \
    const int k0_ = (tt) * 32;                                            \
    GLDS16(Ag + k0_,             (base) + ldsW);                          \
    GLDS16(Bg + k0_,             (base) + 4096 + ldsW);                   \
    GLDS16(Bg + 128l * Cn + k0_, (base) + 8192 + ldsW);                   \
  } while (0)

  const int sc8 = (quad ^ ((r16 >> 1) & 3)) * 8;

  f32x4 acc[4][4];
#pragma unroll
  for (int m = 0; m < 4; m++)
#pragma unroll
    for (int n = 0; n < 4; n++) acc[m][n] = {0.f, 0.f, 0.f, 0.f};

  bf16* bufc = smem;
  bf16* bufn = smem + 12288;
  bf16* bufs = smem + 24576;

  OUT_STAGE(bufc, 0); OUT_STAGE(bufn, 1);
  WAITVM(3);
  BAR();

  bf16x8 af0[2], af1[2], bfr0[4];
#pragma unroll
  for (int n = 0; n < 4; n++)
    bfr0[n] = *(const bf16x8*)&bufc[4096 + (wn + n * 16 + r16) * 32 + sc8];
#pragma unroll
  for (int m = 0; m < 2; m++)
    af0[m] = *(const bf16x8*)&bufc[(wm + m * 16 + r16) * 32 + sc8];

#pragma unroll 3
  for (int tt = 0; tt < NT; ++tt) {
    BAR();
    if (tt + 2 < NT) OUT_STAGE(bufs, tt + 2);
#pragma unroll
    for (int m = 0; m < 2; m++)
      af1[m] = *(const bf16x8*)&bufc[(wm + (m + 2) * 16 + r16) * 32 + sc8];
    __builtin_amdgcn_s_setprio(1);
#pragma unroll
    for (int m = 0; m < 2; m++)
#pragma unroll
      for (int n = 0; n < 4; n++)
        acc[m][n] = __builtin_amdgcn_mfma_f32_16x16x32_bf16(af0[m], bfr0[n], acc[m][n], 0, 0, 0);
    __builtin_amdgcn_s_setprio(0);

    if (tt < NT - 2)       { WAITVM(3); }
    else if (tt == NT - 2) { WAITVM(0); }
    BAR();

    __builtin_amdgcn_s_setprio(1);
#pragma unroll
    for (int m = 0; m < 2; m++)
#pragma unroll
      for (int n = 0; n < 4; n++)
        acc[m + 2][n] = __builtin_amdgcn_mfma_f32_16x16x32_bf16(af1[m], bfr0[n], acc[m + 2][n], 0, 0, 0);
    __builtin_amdgcn_s_setprio(0);

    if (tt + 1 < NT) {
#pragma unroll
      for (int n = 0; n < 4; n++)
        bfr0[n] = *(const bf16x8*)&bufn[4096 + (wn + n * 16 + r16) * 32 + sc8];
#pragma unroll
      for (int m = 0; m < 2; m++)
        af0[m] = *(const bf16x8*)&bufn[(wm + m * 16 + r16) * 32 + sc8];
    }
    bf16* t_ = bufc; bufc = bufn; bufn = bufs; bufs = t_;
  }

  float* Cp = out + (long)b * Cn * S + (long)m0 * S + n0;
#pragma unroll
  for (int m = 0; m < 4; m++)
#pragma unroll
    for (int n = 0; n < 4; n++)
#pragma unroll
      for (int r = 0; r < 4; r++) {
        const int row = wm + m * 16 + quad * 4 + r;
        const int col = wn + n * 16 + r16;
        Cp[(long)row * S + col] = acc[m][n][r];
      }
#undef OUT_STAGE
}

// ---- fused prep: z<4 -> xT[b] = bf16(x[b]^T); z==4 -> weights f32->bf16 ----
__global__ __launch_bounds__(256) void k_prep(
    const float* __restrict__ x, bf16* __restrict__ xT,
    const float* __restrict__ Wqkv, const float* __restrict__ Wout,
    bf16* __restrict__ WqkvB, bf16* __restrict__ WoutB)
{
  __shared__ bf16 tile[32][33];
  if (blockIdx.z < 4) {
    const float* ip = x + (long)blockIdx.z * 1024 * 2048;
    bf16* op = xT + (long)blockIdx.z * 2048 * 1024;
    const int c0 = blockIdx.x * 32, r0 = blockIdx.y * 32;
    const int tx = threadIdx.x & 31, ty = threadIdx.x >> 5;
#pragma unroll
    for (int i = 0; i < 32; i += 8)
      tile[ty + i][tx] = __float2bfloat16(ip[(long)(r0 + ty + i) * 2048 + c0 + tx]);
    __syncthreads();
#pragma unroll
    for (int i = 0; i < 32; i += 8)
      op[(long)(c0 + ty + i) * 1024 + r0 + tx] = tile[tx][ty + i];
  } else {
    const long blk = (long)blockIdx.x + (long)blockIdx.y * 64;
#pragma unroll
    for (int i = 0; i < 2; i++) {
      const long v = blk * 512 + i * 256 + threadIdx.x;
      const bool isQ = v < 786432;
      const float4 f = isQ ? ((const float4*)Wqkv)[v] : ((const float4*)Wout)[v - 786432];
      bf16 tmp[4];
      tmp[0] = __float2bfloat16(f.x);
      tmp[1] = __float2bfloat16(f.y);
      tmp[2] = __float2bfloat16(f.z);
      tmp[3] = __float2bfloat16(f.w);
      ushort4 u = *(ushort4*)tmp;
      if (isQ) ((ushort4*)WqkvB)[v] = u;
      else     ((ushort4*)WoutB)[v - 786432] = u;
    }
  }
}

// ---- MTpart[chunk][z][e][d] = K_h . V_h^T over a 256-wide s-chunk ----
__global__ __launch_bounds__(256) void k_gemm_mt(
    const bf16* __restrict__ KV, float* __restrict__ MTpart)
{
  const int chunk = blockIdx.x;
  const int z = blockIdx.y;
  const int b = z >> 3, h = z & 7;
  const bf16* base = KV + (long)b * 2048 * S;
  const bf16* A  = base + (long)(h * Dh) * S + chunk * 256;
  const bf16* Bp = base + (long)(1024 + h * Dh) * S + chunk * 256;
  f32x4 acc[4][4];
  gemm_bt_core(A, S, Bp, S, 8, acc);
  store_f32_tile(acc, MTpart + ((long)chunk * 32 + z) * (Dh * Dh), Dh);
}

// ---- MbT[z][e][d] = bf16(SCALE * sum_chunk MTpart) ----
__global__ __launch_bounds__(256) void k_reduce_mt(
    const float* __restrict__ MTpart, bf16* __restrict__ MbT)
{
  const long i = (long)blockIdx.x * 256 + threadIdx.x;
  float s = 0.f;
#pragma unroll
  for (int c = 0; c < 8; c++) s += MTpart[(long)c * 32 * Dh * Dh + i];
  MbT[i] = __float2bfloat16(s * SCALE);
}

// ---- W2[b][o][h*128+e] = sum_d Wout[o][h*128+d] * MbT[b,h][e][d] ----
__global__ __launch_bounds__(256) void k_gemm_w2(
    const bf16* __restrict__ WoutB, const bf16* __restrict__ MbT, bf16* __restrict__ W2)
{
  const int m0 = blockIdx.x * 128;
  const int h = blockIdx.y, b = blockIdx.z;
  const int z = b * 8 + h;
  f32x4 acc[4][4];
  gemm_bt_core(WoutB + (long)m0 * Cn + h * Dh, Cn,
               MbT + (long)z * Dh * Dh, Dh, 4, acc);
  store_bf16_tile(acc, W2 + (long)b * Cn * Cn + (long)m0 * Cn + h * Dh, Cn);
}

extern "C" void kernel_launch(void* const* d_in, const int* in_sizes, int n_in,
                              void* d_out, int out_size, void* d_ws, size_t ws_size,
                              hipStream_t stream)
{
  const float* x    = (const float*)d_in[0];  // (4,1024,2048) f32
  const float* Wqkv = (const float*)d_in[1];  // (3072,1024)   f32
  const float* Wout = (const float*)d_in[2];  // (1024,1024)   f32
  float* out = (float*)d_out;                 // (4,1024,2048) f32

  char* ws = (char*)d_ws;
  bf16*  KV     = (bf16*)ws;                     // 33,554,432 B
  bf16*  xT     = (bf16*)(ws + 33554432);        // 16,777,216 B
  bf16*  QT     = (bf16*)(ws + 50331648);        // 16,777,216 B
  bf16*  WqkvB  = (bf16*)(ws + 67108864);        //  6,291,456 B
  bf16*  WoutB  = (bf16*)(ws + 73400320);        //  2,097,152 B
  bf16*  MbT    = (bf16*)(ws + 75497472);        //  1,048,576 B
  bf16*  W2     = (bf16*)(ws + 76546048);        //  8,388,608 B (end 84,934,656)
  bf16*  WkvB   = WqkvB + (long)Cn * Cn;         // K,V rows of WqkvB
  float* MTpart = out;                           // d_out as f32 scratch
                                                 // (dead until k_gemm_out8,
                                                 //  which overwrites fully)

  // prep: xT transpose+cvt (z<4) + weights cvt (z==4), one dispatch
  k_prep<<<dim3(64, 32, 5), 256, 0, stream>>>(x, xT, Wqkv, Wout, WqkvB, WoutB);
  // KV GEMM (blocks 0-511, 256x128 tiles) + QT GEMM (512-767): tail-fill
  k_kvqt8<<<dim3(768), 512, 0, stream>>>(WkvB, xT, KV, WqkvB, QT);
  // MT partials: K_h . V_h^T over 8 s-chunks -> d_out scratch
  k_gemm_mt<<<dim3(8, 32), 256, 0, stream>>>(KV, MTpart);
  // MbT = bf16(SCALE * sum of partials)
  k_reduce_mt<<<dim3(2048), 256, 0, stream>>>(MTpart, MbT);
  // W2[b] = Wout . blockdiag(scale*M): folded output weights
  k_gemm_w2<<<dim3(8, 8, 4), 256, 0, stream>>>(WoutB, MbT, W2);
  // out[b] = W2[b] . Q[b]  (f32 output, overwrites scratch)
  k_gemm_out8<<<dim3(256), 512, 0, stream>>>(W2, QT, out);
}

// Round 7
// 194.854 us; speedup vs baseline: 1.0161x; 1.0089x over previous
//
#include <hip/hip_runtime.h>
#include <hip/hip_bf16.h>
#include <stdint.h>

using bf16 = __hip_bfloat16;

typedef __bf16 bf16x8 __attribute__((ext_vector_type(8)));
typedef float  f32x4  __attribute__((ext_vector_type(4)));

constexpr int Bc = 4, Hh = 8, Dh = 128, S = 2048, Cn = 1024, O3 = 3072;
constexpr float SCALE = 0.08838834764831845f;  // 1/sqrt(128)

// async global->LDS, 16B per lane, wave-uniform LDS base + lane*16 scatter
#define GLDS16(gp, lp)                                               \
  __builtin_amdgcn_global_load_lds(                                  \
      (const __attribute__((address_space(1))) void*)(gp),           \
      (__attribute__((address_space(3))) void*)(lp), 16, 0, 0)

#define WAITVM(N) asm volatile("s_waitcnt vmcnt(" #N ")" ::: "memory")
#define BAR()                                  \
  do {                                         \
    asm volatile("" ::: "memory");             \
    __builtin_amdgcn_s_barrier();              \
    asm volatile("" ::: "memory");             \
  } while (0)

// ---------------------------------------------------------------------------
// BT-GEMM core (m97 structure): 128x128 tile, 256 threads = 4 waves.
// Used by the small GEMMs (mt, w2).
// ---------------------------------------------------------------------------
__device__ __forceinline__ void gemm_bt_core(
    const bf16* __restrict__ Abase, int lda,
    const bf16* __restrict__ Bbase, int ldb,
    int kIters, f32x4 (&acc)[4][4])
{
  alignas(16) __shared__ bf16 As[128 * 32];
  alignas(16) __shared__ bf16 Bs[128 * 32];
  const int t    = threadIdx.x;
  const int lane = t & 63;
  const int quad = lane >> 4, r16 = lane & 15;
  const int wave = t >> 6;
  const int wm = (wave & 1) * 64, wn = (wave >> 1) * 64;
  const int lrow = lane >> 2;
  const int lk   = (lane & 3) * 8;

  const long aOff0 = (long)(wave * 32 + lrow) * lda + lk;
  const long aOff1 = aOff0 + 16l * lda;
  const long bOff0 = (long)(wave * 32 + lrow) * ldb + lk;
  const long bOff1 = bOff0 + 16l * ldb;
  bf16* aL0 = &As[(wave * 32) * 32];
  bf16* aL1 = &As[(wave * 32 + 16) * 32];
  bf16* bL0 = &Bs[(wave * 32) * 32];
  bf16* bL1 = &Bs[(wave * 32 + 16) * 32];

#pragma unroll
  for (int i = 0; i < 4; i++)
#pragma unroll
    for (int j = 0; j < 4; j++) acc[i][j] = {0.f, 0.f, 0.f, 0.f};

  for (int ks = 0; ks < kIters; ++ks) {
    const int k0 = ks * 32;
    __syncthreads();
    GLDS16(Abase + k0 + aOff0, aL0);
    GLDS16(Abase + k0 + aOff1, aL1);
    GLDS16(Bbase + k0 + bOff0, bL0);
    GLDS16(Bbase + k0 + bOff1, bL1);
    __syncthreads();
    bf16x8 af[4], bfr[4];
#pragma unroll
    for (int i = 0; i < 4; i++)
      af[i] = *(const bf16x8*)&As[(wm + i * 16 + r16) * 32 + quad * 8];
#pragma unroll
    for (int j = 0; j < 4; j++)
      bfr[j] = *(const bf16x8*)&Bs[(wn + j * 16 + r16) * 32 + quad * 8];
#pragma unroll
    for (int i = 0; i < 4; i++)
#pragma unroll
      for (int j = 0; j < 4; j++)
        acc[i][j] = __builtin_amdgcn_mfma_f32_16x16x32_bf16(af[i], bfr[j], acc[i][j], 0, 0, 0);
  }
}

__device__ __forceinline__ void store_bf16_tile(
    f32x4 (&acc)[4][4], bf16* __restrict__ Cp, int ldc)
{
  const int t = threadIdx.x;
  const int lane = t & 63;
  const int quad = lane >> 4, r16 = lane & 15;
  const int wave = t >> 6;
  const int wm = (wave & 1) * 64, wn = (wave >> 1) * 64;
#pragma unroll
  for (int i = 0; i < 4; i++)
#pragma unroll
    for (int j = 0; j < 4; j++)
#pragma unroll
      for (int r = 0; r < 4; r++) {
        const int row = wm + i * 16 + quad * 4 + r;
        const int col = wn + j * 16 + r16;
        Cp[(long)row * ldc + col] = __float2bfloat16(acc[i][j][r]);
      }
}

__device__ __forceinline__ void store_f32_tile(
    f32x4 (&acc)[4][4], float* __restrict__ Cp, int ldc)
{
  const int t = threadIdx.x;
  const int lane = t & 63;
  const int quad = lane >> 4, r16 = lane & 15;
  const int wave = t >> 6;
  const int wm = (wave & 1) * 64, wn = (wave >> 1) * 64;
#pragma unroll
  for (int i = 0; i < 4; i++)
#pragma unroll
    for (int j = 0; j < 4; j++)
#pragma unroll
      for (int r = 0; r < 4; r++) {
        const int row = wm + i * 16 + quad * 4 + r;
        const int col = wn + j * 16 + r16;
        Cp[(long)row * ldc + col] = acc[i][j][r];
      }
}

// ---------------------------------------------------------------------------
// 256x256 pipelined GEMM for KV = Wkv . x  (BT form, all batches).
//   M=2048, N=8192, K=1024. 256 blocks x 512 threads, 4 LDS buffers (128 KiB).
// 128x64 acc/wave: LDS-read/FLOP = 24 B/kFLOP < 85 B/cy ceiling (balanced).
// Per K-tile, 2 barriers with ds_read/MFMA overlap (verified r3/r4):
//   [BAR A] stage(t+3) | ds_read(p2 A-frags) | MFMA p1 (regs preloaded)
//   vmcnt(8) [BAR B]   MFMA p2 | ds_read(tile t+1 p1 frags)
// XCD grouping (verified r4): XCD = orig&7 owns 4 nt x all 8 mt.
// ---------------------------------------------------------------------------
__global__ __launch_bounds__(512, 2) void k_gemm_kv8(
    const bf16* __restrict__ WkvB, const bf16* __restrict__ xT, bf16* __restrict__ KV)
{
  constexpr int NT = Cn / 32;  // 32 K-tiles
  alignas(16) __shared__ bf16 smem[4 * 16384];  // 4 x (A 8192 + B 8192)

  const int orig = blockIdx.x;
  const int mt = orig >> 5;                               // 0..7  (o' tile)
  const int nt = ((orig & 7) << 2) | ((orig >> 3) & 3);   // 0..31 (s tile)
  const int m0 = mt * 256;

  const int tid  = threadIdx.x;
  const int lane = tid & 63;
  const int w    = tid >> 6;
  const int quad = lane >> 4, r16 = lane & 15;
  const int wm = (w >> 2) * 128;
  const int wn = (w & 3) * 64;

  const int srow = w * 16 + (lane >> 2);
  const int cx   = (lane & 3) ^ ((lane >> 3) & 3);   // inverse-swizzled k-chunk
  const bf16* Ag = WkvB + (long)(m0 + srow) * Cn + cx * 8;
  const bf16* Bg = xT + (long)((long)nt * 256 + srow) * Cn + cx * 8;
  const int ldsW = w * 512;

#define KV8_STAGE_A(tt)                                                   \
  do {                                                                    \
    const int k0_ = (tt) * 32, bb_ = ((tt) & 3) * 16384;                  \
    GLDS16(Ag + k0_,             &smem[bb_ + ldsW]);                      \
    GLDS16(Ag + 128l * Cn + k0_, &smem[bb_ + 4096 + ldsW]);               \
  } while (0)
#define KV8_STAGE_B(tt)                                                   \
  do {                                                                    \
    const int k0_ = (tt) * 32, bb_ = ((tt) & 3) * 16384;                  \
    GLDS16(Bg + k0_,             &smem[bb_ + 8192 + ldsW]);               \
    GLDS16(Bg + 128l * Cn + k0_, &smem[bb_ + 8192 + 4096 + ldsW]);        \
  } while (0)

  const int sc8 = (quad ^ ((r16 >> 1) & 3)) * 8;  // swizzled chunk, 2-way=free

  f32x4 acc[8][4];
#pragma unroll
  for (int m = 0; m < 8; m++)
#pragma unroll
    for (int n = 0; n < 4; n++) acc[m][n] = {0.f, 0.f, 0.f, 0.f};

  // prologue: stage tiles 0,1,2 (12 loads/wave); retire tile 0's 4
  KV8_STAGE_A(0); KV8_STAGE_B(0);
  KV8_STAGE_A(1); KV8_STAGE_B(1);
  KV8_STAGE_A(2); KV8_STAGE_B(2);
  WAITVM(8);
  BAR();

  bf16x8 af0[4], bfr0[4], af1[4];
  {  // preload tile 0 phase-1 fragments
    const bf16* Ab = &smem[0];
    const bf16* Bb = Ab + 8192;
#pragma unroll
    for (int n = 0; n < 4; n++)
      bfr0[n] = *(const bf16x8*)&Bb[(wn + n * 16 + r16) * 32 + sc8];
#pragma unroll
    for (int m = 0; m < 4; m++)
      af0[m] = *(const bf16x8*)&Ab[(wm + m * 16 + r16) * 32 + sc8];
  }

#pragma unroll 4
  for (int tt = 0; tt < NT; ++tt) {
    const bf16* Ab = &smem[(tt & 3) * 16384];

    BAR();  // BAR A: buf (t-1)&3 fully read -> safe to stage t+3 into it
    if (tt + 3 < NT) { KV8_STAGE_A(tt + 3); KV8_STAGE_B(tt + 3); }
#pragma unroll
    for (int m = 0; m < 4; m++)
      af1[m] = *(const bf16x8*)&Ab[(wm + (m + 4) * 16 + r16) * 32 + sc8];
    __builtin_amdgcn_s_setprio(1);
#pragma unroll
    for (int m = 0; m < 4; m++)
#pragma unroll
      for (int n = 0; n < 4; n++)
        acc[m][n] = __builtin_amdgcn_mfma_f32_16x16x32_bf16(af0[m], bfr0[n], acc[m][n], 0, 0, 0);
    __builtin_amdgcn_s_setprio(0);

    if (tt <= NT - 4)      { WAITVM(8); }
    else if (tt == NT - 3) { WAITVM(4); }
    else if (tt == NT - 2) { WAITVM(0); }
    BAR();  // BAR B: every wave's vmcnt retired tile t+1 -> buf t+1 readable

    __builtin_amdgcn_s_setprio(1);
#pragma unroll
    for (int m = 0; m < 4; m++)
#pragma unroll
      for (int n = 0; n < 4; n++)
        acc[m + 4][n] = __builtin_amdgcn_mfma_f32_16x16x32_bf16(af1[m], bfr0[n], acc[m + 4][n], 0, 0, 0);
    __builtin_amdgcn_s_setprio(0);

    if (tt + 1 < NT) {  // look-ahead: tile t+1 phase-1 fragments
      const bf16* Ab2 = &smem[((tt + 1) & 3) * 16384];
      const bf16* Bb2 = Ab2 + 8192;
#pragma unroll
      for (int n = 0; n < 4; n++)
        bfr0[n] = *(const bf16x8*)&Bb2[(wn + n * 16 + r16) * 32 + sc8];
#pragma unroll
      for (int m = 0; m < 4; m++)
        af0[m] = *(const bf16x8*)&Ab2[(wm + m * 16 + r16) * 32 + sc8];
    }
  }

  // epilogue: per-wave 128x64 sub-tile -> KV[b][o'][s]
  bf16* Cp = KV + (long)(nt >> 3) * 2048 * S + (long)m0 * S + (nt & 7) * 256;
#pragma unroll
  for (int m = 0; m < 8; m++)
#pragma unroll
    for (int n = 0; n < 4; n++)
#pragma unroll
      for (int r = 0; r < 4; r++) {
        const int row = wm + m * 16 + quad * 4 + r;
        const int col = wn + n * 16 + r16;
        Cp[(long)row * S + col] = __float2bfloat16(acc[m][n][r]);
      }
#undef KV8_STAGE_A
#undef KV8_STAGE_B
}

// ---------------------------------------------------------------------------
// qt: QT[b][s][u] = xT . Wq^T, tile 128(s) x 256(u), 3 LDS buffers (72 KiB),
// 2 blocks/CU. 64x64/wave is LDS-ratio-bound -> occupancy overlap pays here.
// Window t: [BAR A] stage(t+2) | ds_read af1 | MFMA p1
//           vmcnt(3) [BAR B] MFMA p2 | lookahead(t+1)
// ---------------------------------------------------------------------------
__global__ __launch_bounds__(512, 4) void k_gemm_qt8(
    const bf16* __restrict__ xT, const bf16* __restrict__ WqB, bf16* __restrict__ QT)
{
  constexpr int NT = Cn / 32;
  alignas(16) __shared__ bf16 smem[3 * 12288];  // 72 KiB

  const int orig = blockIdx.x;
  const int b  = orig >> 6;          // 0..3
  const int mt = (orig >> 2) & 15;   // 0..15
  const int nt = orig & 3;           // 0..3
  const int m0 = mt * 128, n0 = nt * 256;

  const int tid  = threadIdx.x;
  const int lane = tid & 63;
  const int w    = tid >> 6;
  const int quad = lane >> 4, r16 = lane & 15;
  const int wm = (w >> 2) * 64;   // 2 M-groups
  const int wn = (w & 3) * 64;    // 4 N-groups

  const int srow = w * 16 + (lane >> 2);
  const int cx   = (lane & 3) ^ ((lane >> 3) & 3);
  const bf16* Ag = xT + (long)b * S * Cn + (long)(m0 + srow) * Cn + cx * 8;
  const bf16* Bg = WqB + (long)(n0 + srow) * Cn + cx * 8;
  const int ldsW = w * 512;

#define QT_STAGE(base, tt)                                                \
  do {                                                                    \
    const int k0_ = (tt) * 32;                                            \
    GLDS16(Ag + k0_,             (base) + ldsW);                          \
    GLDS16(Bg + k0_,             (base) + 4096 + ldsW);                   \
    GLDS16(Bg + 128l * Cn + k0_, (base) + 8192 + ldsW);                   \
  } while (0)

  const int sc8 = (quad ^ ((r16 >> 1) & 3)) * 8;

  f32x4 acc[4][4];
#pragma unroll
  for (int m = 0; m < 4; m++)
#pragma unroll
    for (int n = 0; n < 4; n++) acc[m][n] = {0.f, 0.f, 0.f, 0.f};

  bf16* bufc = smem;
  bf16* bufn = smem + 12288;
  bf16* bufs = smem + 24576;

  QT_STAGE(bufc, 0); QT_STAGE(bufn, 1);
  WAITVM(3);
  BAR();

  bf16x8 af0[2], af1[2], bfr0[4];
#pragma unroll
  for (int n = 0; n < 4; n++)
    bfr0[n] = *(const bf16x8*)&bufc[4096 + (wn + n * 16 + r16) * 32 + sc8];
#pragma unroll
  for (int m = 0; m < 2; m++)
    af0[m] = *(const bf16x8*)&bufc[(wm + m * 16 + r16) * 32 + sc8];

#pragma unroll 3
  for (int tt = 0; tt < NT; ++tt) {
    BAR();
    if (tt + 2 < NT) QT_STAGE(bufs, tt + 2);
#pragma unroll
    for (int m = 0; m < 2; m++)
      af1[m] = *(const bf16x8*)&bufc[(wm + (m + 2) * 16 + r16) * 32 + sc8];
    __builtin_amdgcn_s_setprio(1);
#pragma unroll
    for (int m = 0; m < 2; m++)
#pragma unroll
      for (int n = 0; n < 4; n++)
        acc[m][n] = __builtin_amdgcn_mfma_f32_16x16x32_bf16(af0[m], bfr0[n], acc[m][n], 0, 0, 0);
    __builtin_amdgcn_s_setprio(0);

    if (tt < NT - 2)       { WAITVM(3); }
    else if (tt == NT - 2) { WAITVM(0); }
    BAR();

    __builtin_amdgcn_s_setprio(1);
#pragma unroll
    for (int m = 0; m < 2; m++)
#pragma unroll
      for (int n = 0; n < 4; n++)
        acc[m + 2][n] = __builtin_amdgcn_mfma_f32_16x16x32_bf16(af1[m], bfr0[n], acc[m + 2][n], 0, 0, 0);
    __builtin_amdgcn_s_setprio(0);

    if (tt + 1 < NT) {
#pragma unroll
      for (int n = 0; n < 4; n++)
        bfr0[n] = *(const bf16x8*)&bufn[4096 + (wn + n * 16 + r16) * 32 + sc8];
#pragma unroll
      for (int m = 0; m < 2; m++)
        af0[m] = *(const bf16x8*)&bufn[(wm + m * 16 + r16) * 32 + sc8];
    }
    bf16* t_ = bufc; bufc = bufn; bufn = bufs; bufs = t_;
  }

  bf16* Cp = QT + (long)b * S * Cn + (long)m0 * Cn + n0;
#pragma unroll
  for (int m = 0; m < 4; m++)
#pragma unroll
    for (int n = 0; n < 4; n++)
#pragma unroll
      for (int r = 0; r < 4; r++) {
        const int row = wm + m * 16 + quad * 4 + r;
        const int col = wn + n * 16 + r16;
        Cp[(long)row * Cn + col] = __float2bfloat16(acc[m][n][r]);
      }
#undef QT_STAGE
}

// ---- out = W2[b] . Q[b] -> f32, tile 128(o) x 256(s), 72 KiB, 2 blk/CU ----
__global__ __launch_bounds__(512, 4) void k_gemm_out8(
    const bf16* __restrict__ W2, const bf16* __restrict__ QT, float* __restrict__ out)
{
  constexpr int NT = Cn / 32;
  alignas(16) __shared__ bf16 smem[3 * 12288];  // 72 KiB

  const int orig = blockIdx.x;
  const int swz  = (orig & 7) * 32 + (orig >> 3);
  const int b  = swz >> 6;
  const int mt = (swz >> 3) & 7;
  const int nt = swz & 7;
  const int m0 = mt * 128, n0 = nt * 256;

  const int tid  = threadIdx.x;
  const int lane = tid & 63;
  const int w    = tid >> 6;
  const int quad = lane >> 4, r16 = lane & 15;
  const int wm = (w >> 2) * 64;
  const int wn = (w & 3) * 64;

  const int srow = w * 16 + (lane >> 2);
  const int cx   = (lane & 3) ^ ((lane >> 3) & 3);
  const bf16* Ag = W2 + (long)b * Cn * Cn + (long)(m0 + srow) * Cn + cx * 8;
  const bf16* Bg = QT + (long)b * S * Cn + (long)(n0 + srow) * Cn + cx * 8;
  const int ldsW = w * 512;

#define OUT_STAGE(base, tt)                                               \
  do {                                                                    \
    const int k0_ = (tt) * 32;                                            \
    GLDS16(Ag + k0_,             (base) + ldsW);                          \
    GLDS16(Bg + k0_,             (base) + 4096 + ldsW);                   \
    GLDS16(Bg + 128l * Cn + k0_, (base) + 8192 + ldsW);                   \
  } while (0)

  const int sc8 = (quad ^ ((r16 >> 1) & 3)) * 8;

  f32x4 acc[4][4];
#pragma unroll
  for (int m = 0; m < 4; m++)
#pragma unroll
    for (int n = 0; n < 4; n++) acc[m][n] = {0.f, 0.f, 0.f, 0.f};

  bf16* bufc = smem;
  bf16* bufn = smem + 12288;
  bf16* bufs = smem + 24576;

  OUT_STAGE(bufc, 0); OUT_STAGE(bufn, 1);
  WAITVM(3);
  BAR();

  bf16x8 af0[2], af1[2], bfr0[4];
#pragma unroll
  for (int n = 0; n < 4; n++)
    bfr0[n] = *(const bf16x8*)&bufc[4096 + (wn + n * 16 + r16) * 32 + sc8];
#pragma unroll
  for (int m = 0; m < 2; m++)
    af0[m] = *(const bf16x8*)&bufc[(wm + m * 16 + r16) * 32 + sc8];

#pragma unroll 3
  for (int tt = 0; tt < NT; ++tt) {
    BAR();
    if (tt + 2 < NT) OUT_STAGE(bufs, tt + 2);
#pragma unroll
    for (int m = 0; m < 2; m++)
      af1[m] = *(const bf16x8*)&bufc[(wm + (m + 2) * 16 + r16) * 32 + sc8];
    __builtin_amdgcn_s_setprio(1);
#pragma unroll
    for (int m = 0; m < 2; m++)
#pragma unroll
      for (int n = 0; n < 4; n++)
        acc[m][n] = __builtin_amdgcn_mfma_f32_16x16x32_bf16(af0[m], bfr0[n], acc[m][n], 0, 0, 0);
    __builtin_amdgcn_s_setprio(0);

    if (tt < NT - 2)       { WAITVM(3); }
    else if (tt == NT - 2) { WAITVM(0); }
    BAR();

    __builtin_amdgcn_s_setprio(1);
#pragma unroll
    for (int m = 0; m < 2; m++)
#pragma unroll
      for (int n = 0; n < 4; n++)
        acc[m + 2][n] = __builtin_amdgcn_mfma_f32_16x16x32_bf16(af1[m], bfr0[n], acc[m + 2][n], 0, 0, 0);
    __builtin_amdgcn_s_setprio(0);

    if (tt + 1 < NT) {
#pragma unroll
      for (int n = 0; n < 4; n++)
        bfr0[n] = *(const bf16x8*)&bufn[4096 + (wn + n * 16 + r16) * 32 + sc8];
#pragma unroll
      for (int m = 0; m < 2; m++)
        af0[m] = *(const bf16x8*)&bufn[(wm + m * 16 + r16) * 32 + sc8];
    }
    bf16* t_ = bufc; bufc = bufn; bufn = bufs; bufs = t_;
  }

  float* Cp = out + (long)b * Cn * S + (long)m0 * S + n0;
#pragma unroll
  for (int m = 0; m < 4; m++)
#pragma unroll
    for (int n = 0; n < 4; n++)
#pragma unroll
      for (int r = 0; r < 4; r++) {
        const int row = wm + m * 16 + quad * 4 + r;
        const int col = wn + n * 16 + r16;
        Cp[(long)row * S + col] = acc[m][n][r];
      }
#undef OUT_STAGE
}

// ---- fused prep: z<4 -> xT[b] = bf16(x[b]^T); z==4 -> weights f32->bf16 ----
__global__ __launch_bounds__(256) void k_prep(
    const float* __restrict__ x, bf16* __restrict__ xT,
    const float* __restrict__ Wqkv, const float* __restrict__ Wout,
    bf16* __restrict__ WqkvB, bf16* __restrict__ WoutB)
{
  __shared__ bf16 tile[32][33];
  if (blockIdx.z < 4) {
    const float* ip = x + (long)blockIdx.z * 1024 * 2048;
    bf16* op = xT + (long)blockIdx.z * 2048 * 1024;
    const int c0 = blockIdx.x * 32, r0 = blockIdx.y * 32;
    const int tx = threadIdx.x & 31, ty = threadIdx.x >> 5;
#pragma unroll
    for (int i = 0; i < 32; i += 8)
      tile[ty + i][tx] = __float2bfloat16(ip[(long)(r0 + ty + i) * 2048 + c0 + tx]);
    __syncthreads();
#pragma unroll
    for (int i = 0; i < 32; i += 8)
      op[(long)(c0 + ty + i) * 1024 + r0 + tx] = tile[tx][ty + i];
  } else {
    const long blk = (long)blockIdx.x + (long)blockIdx.y * 64;
#pragma unroll
    for (int i = 0; i < 2; i++) {
      const long v = blk * 512 + i * 256 + threadIdx.x;
      const bool isQ = v < 786432;
      const float4 f = isQ ? ((const float4*)Wqkv)[v] : ((const float4*)Wout)[v - 786432];
      bf16 tmp[4];
      tmp[0] = __float2bfloat16(f.x);
      tmp[1] = __float2bfloat16(f.y);
      tmp[2] = __float2bfloat16(f.z);
      tmp[3] = __float2bfloat16(f.w);
      ushort4 u = *(ushort4*)tmp;
      if (isQ) ((ushort4*)WqkvB)[v] = u;
      else     ((ushort4*)WoutB)[v - 786432] = u;
    }
  }
}

// ---- MTpart[chunk][z][e][d] = K_h . V_h^T over a 256-wide s-chunk ----
__global__ __launch_bounds__(256) void k_gemm_mt(
    const bf16* __restrict__ KV, float* __restrict__ MTpart)
{
  const int chunk = blockIdx.x;
  const int z = blockIdx.y;
  const int b = z >> 3, h = z & 7;
  const bf16* base = KV + (long)b * 2048 * S;
  const bf16* A  = base + (long)(h * Dh) * S + chunk * 256;
  const bf16* Bp = base + (long)(1024 + h * Dh) * S + chunk * 256;
  f32x4 acc[4][4];
  gemm_bt_core(A, S, Bp, S, 8, acc);
  store_f32_tile(acc, MTpart + ((long)chunk * 32 + z) * (Dh * Dh), Dh);
}

// ---- MbT[z][e][d] = bf16(SCALE * sum_chunk MTpart) ----
__global__ __launch_bounds__(256) void k_reduce_mt(
    const float* __restrict__ MTpart, bf16* __restrict__ MbT)
{
  const long i = (long)blockIdx.x * 256 + threadIdx.x;
  float s = 0.f;
#pragma unroll
  for (int c = 0; c < 8; c++) s += MTpart[(long)c * 32 * Dh * Dh + i];
  MbT[i] = __float2bfloat16(s * SCALE);
}

// ---- W2[b][o][h*128+e] = sum_d Wout[o][h*128+d] * MbT[b,h][e][d] ----
__global__ __launch_bounds__(256) void k_gemm_w2(
    const bf16* __restrict__ WoutB, const bf16* __restrict__ MbT, bf16* __restrict__ W2)
{
  const int m0 = blockIdx.x * 128;
  const int h = blockIdx.y, b = blockIdx.z;
  const int z = b * 8 + h;
  f32x4 acc[4][4];
  gemm_bt_core(WoutB + (long)m0 * Cn + h * Dh, Cn,
               MbT + (long)z * Dh * Dh, Dh, 4, acc);
  store_bf16_tile(acc, W2 + (long)b * Cn * Cn + (long)m0 * Cn + h * Dh, Cn);
}

extern "C" void kernel_launch(void* const* d_in, const int* in_sizes, int n_in,
                              void* d_out, int out_size, void* d_ws, size_t ws_size,
                              hipStream_t stream)
{
  const float* x    = (const float*)d_in[0];  // (4,1024,2048) f32
  const float* Wqkv = (const float*)d_in[1];  // (3072,1024)   f32
  const float* Wout = (const float*)d_in[2];  // (1024,1024)   f32
  float* out = (float*)d_out;                 // (4,1024,2048) f32

  char* ws = (char*)d_ws;
  bf16*  KV     = (bf16*)ws;                     // 33,554,432 B
  bf16*  xT     = (bf16*)(ws + 33554432);        // 16,777,216 B
  bf16*  QT     = (bf16*)(ws + 50331648);        // 16,777,216 B
  bf16*  WqkvB  = (bf16*)(ws + 67108864);        //  6,291,456 B
  bf16*  WoutB  = (bf16*)(ws + 73400320);        //  2,097,152 B
  bf16*  MbT    = (bf16*)(ws + 75497472);        //  1,048,576 B
  bf16*  W2     = (bf16*)(ws + 76546048);        //  8,388,608 B (end 84,934,656)
  bf16*  WkvB   = WqkvB + (long)Cn * Cn;         // K,V rows of WqkvB
  float* MTpart = out;                           // d_out as f32 scratch
                                                 // (dead until k_gemm_out8,
                                                 //  which overwrites fully)

  // prep: xT transpose+cvt (z<4) + weights cvt (z==4), one dispatch
  k_prep<<<dim3(64, 32, 5), 256, 0, stream>>>(x, xT, Wqkv, Wout, WqkvB, WoutB);
  // KV GEMM: 256x256 tiles, 128x64/wave (LDS-balanced), 1 block/CU
  k_gemm_kv8<<<dim3(256), 512, 0, stream>>>(WkvB, xT, KV);
  // QT GEMM: 128x256 tiles, 2 blocks/CU
  k_gemm_qt8<<<dim3(256), 512, 0, stream>>>(xT, WqkvB, QT);
  // MT partials: K_h . V_h^T over 8 s-chunks -> d_out scratch
  k_gemm_mt<<<dim3(8, 32), 256, 0, stream>>>(KV, MTpart);
  // MbT = bf16(SCALE * sum of partials)
  k_reduce_mt<<<dim3(2048), 256, 0, stream>>>(MTpart, MbT);
  // W2[b] = Wout . blockdiag(scale*M): folded output weights
  k_gemm_w2<<<dim3(8, 8, 4), 256, 0, stream>>>(WoutB, MbT, W2);
  // out[b] = W2[b] . Q[b]  (f32 output, overwrites scratch)
  k_gemm_out8<<<dim3(256), 512, 0, stream>>>(W2, QT, out);
}